// Round 1
// 659.744 us; speedup vs baseline: 1.2601x; 1.2601x over previous
//
#include <hip/hip_runtime.h>
#include <math.h>

#define IMG_H 1024
#define IMG_W 1024
#define KS 5
#define PAD 2
#define RPB 16                  // output rows per block (vertical register tile)
#define NIT (RPB + KS - 1)      // 20 input rows streamed per block

// Compute the horizontal (j) min for one filter row over 4 output columns and
// merge into the accumulator. All indices are compile-time after inlining, so
// w/a stay in registers.
__device__ __forceinline__ void rowmin_merge(const float* __restrict__ w,
                                             const float* __restrict__ Fr,
                                             float* __restrict__ a,
                                             bool init)
{
#pragma unroll
    for (int col = 0; col < 4; ++col) {
        float m =        w[col + 0] - Fr[0];
        m = fminf(m,     w[col + 1] - Fr[1]);
        m = fminf(m,     w[col + 2] - Fr[2]);
        m = fminf(m,     w[col + 3] - Fr[3]);
        m = fminf(m,     w[col + 4] - Fr[4]);
        a[col] = init ? m : fminf(a[col], m);
    }
}

__global__ __launch_bounds__(256)
void erosion5x5_kernel(const float* __restrict__ img,
                       const float* __restrict__ filt,
                       float* __restrict__ out)
{
    const int tid = threadIdx.x;

    // --- XCD-bijective block swizzle: give each XCD a contiguous chunk of
    // logical tiles so vertically-neighboring tiles (which share a 4-row halo)
    // hit the same per-XCD L2. nwg = 64*96 = 6144, divisible by 8.
    int bid = blockIdx.x;
    const int nwg = gridDim.x;
    if ((nwg & 7) == 0) {
        bid = (bid & 7) * (nwg >> 3) + (bid >> 3);
    }

    const int tiles_per_plane = IMG_H / RPB;        // 64
    const int tile = bid % tiles_per_plane;
    const int bc   = bid / tiles_per_plane;         // fused batch*channel plane
    const int y0   = tile * RPB;                    // first output row of tile
    const int x0   = tid * 4;                       // 4 output columns/thread

    // Preload 5x5 filter (uniform address -> scalar loads into SGPRs)
    float F[25];
#pragma unroll
    for (int i = 0; i < 25; ++i) F[i] = filt[i];

    const size_t plane = (size_t)bc * (IMG_H * IMG_W);
    const float* base  = img + plane;
    float* obase       = out + plane;

    // Ring of 5 in-flight output rows (slot = ly % 5). Fully static indexing.
    float acc[KS][4];

    const bool fast = (x0 >= 4) && (x0 + 8 <= IMG_W);

#pragma unroll
    for (int rr = 0; rr < NIT; ++rr) {
        const int r = y0 - PAD + rr;                // global input row
        const bool rvalid = (r >= 0) && (r < IMG_H);

        // 8-wide column window x0-2 .. x0+5
        float w[8];
        if (rvalid) {
            const float* row = base + (size_t)r * IMG_W;
            if (fast) {
                // 3 aligned float4 loads covering x0-4 .. x0+7 (overlap = L1 hits)
                float4 a4 = *(const float4*)(row + x0 - 4);
                float4 b4 = *(const float4*)(row + x0);
                float4 d4 = *(const float4*)(row + x0 + 4);
                w[0] = a4.z; w[1] = a4.w;
                w[2] = b4.x; w[3] = b4.y; w[4] = b4.z; w[5] = b4.w;
                w[6] = d4.x; w[7] = d4.y;
            } else {
                // edge threads (x0 == 0 or x0 == 1020): +inf fill
#pragma unroll
                for (int t = 0; t < 8; ++t) {
                    int x = x0 - 2 + t;
                    w[t] = (x >= 0 && x < IMG_W) ? row[x] : INFINITY;
                }
            }
        }

        // Input row rr contributes to output rows ly = rr-4 .. rr via filter
        // row i = rr - ly. i == 0 is the first touch of slot ly%5.
#pragma unroll
        for (int i = 0; i < KS; ++i) {
            const int ly = rr - i;
            if (ly < 0 || ly >= RPB) continue;       // compile-time prune
            float* a = acc[ly % KS];
            if (i == 0) {
                if (rvalid) {
                    rowmin_merge(w, &F[0], a, true);
                } else {
                    a[0] = INFINITY; a[1] = INFINITY;
                    a[2] = INFINITY; a[3] = INFINITY;
                }
            } else if (rvalid) {
                rowmin_merge(w, &F[i * KS], a, false);
            }
        }

        // Output row ly = rr - 4 is complete; store it.
        if (rr >= KS - 1) {
            const int ly = rr - (KS - 1);
            const float* a = acc[ly % KS];
            float4 o;
            o.x = a[0]; o.y = a[1]; o.z = a[2]; o.w = a[3];
            *(float4*)(obase + (size_t)(y0 + ly) * IMG_W + x0) = o;
        }
    }
}

extern "C" void kernel_launch(void* const* d_in, const int* in_sizes, int n_in,
                              void* d_out, int out_size, void* d_ws, size_t ws_size,
                              hipStream_t stream) {
    const float* img  = (const float*)d_in[0];
    const float* filt = (const float*)d_in[1];
    float* out = (float*)d_out;

    const int n_planes = in_sizes[0] / (IMG_H * IMG_W);  // 32*3 = 96
    const int tiles_per_plane = IMG_H / RPB;             // 64

    dim3 grid(tiles_per_plane * n_planes);               // 6144 blocks
    dim3 block(256);
    erosion5x5_kernel<<<grid, block, 0, stream>>>(img, filt, out);
}